// Round 3
// baseline (294.000 us; speedup 1.0000x reference)
//
#include <hip/hip_runtime.h>
#include <math.h>

// Problem constants (B=2, N=512, C=64, H=8)
constexpr int BDIM = 512;
constexpr int NDIM = 512;
constexpr int CDIM = 64;
constexpr int HDIM = 8;
constexpr int NWAVE = BDIM / 64;

// One block per (b,m); thread t owns row n = t. Direct per-row float4 loads
// (R0 pattern — R2 proved coalescing shape is NOT the limiter), restructured
// for maximum memory-level parallelism:
//   - ALL 32 float4 loads (full q-row + full k-row, 8 KB/thread... 128 B/thread,
//     8 KB/wave) are issued before the first FMA in program order.
//   - __launch_bounds__(512, 2): VGPR cap 128 (was 64 -> compiler re-rolled to
//     a serial load->drain->compute pattern at VGPR=28..32 in R0/R2; that
//     serialization capped delivered BW at ~2.4 TB/s = latency-bound).
//   - Compiler slides the k-load tail into the q-FMAs under register pressure,
//     emitting counted vmcnt(N) waits -> loads stay in flight continuously.
// 2 blocks/CU (16 waves) at VGPR<=128; LDS is only the 544 B reduction bufs.
__global__ __launch_bounds__(BDIM, 2)
void mha_kernel(const float* __restrict__ q,
                const float* __restrict__ kk,
                const float* __restrict__ mask,
                const float* __restrict__ W,      // (H, 2C) row-major
                const float* __restrict__ bias,   // (H,)
                float* __restrict__ out)          // (B, N, N, H)
{
    __shared__ float red[NWAVE * HDIM];
    __shared__ float rsum_lds[HDIM];

    const int bm = blockIdx.x;      // b*512 + m
    const int t  = threadIdx.x;

    const float4* qp = (const float4*)(q  + (size_t)bm * NDIM * CDIM + (size_t)t * CDIM);
    const float4* kp = (const float4*)(kk + (size_t)bm * NDIM * CDIM + (size_t)t * CDIM);

    // ---- Phase A: issue EVERYTHING ----
    float4 xq[16];
    float4 xk[16];
#pragma unroll
    for (int j = 0; j < 16; ++j) xq[j] = qp[j];
#pragma unroll
    for (int j = 0; j < 16; ++j) xk[j] = kp[j];
    const float mval = mask[bm * NDIM + t];

    // ---- Phase B: FMA with SGPR-resident W (wave-uniform address) ----
    float acc[HDIM];
#pragma unroll
    for (int h = 0; h < HDIM; ++h) acc[h] = 0.0f;

#pragma unroll
    for (int h = 0; h < HDIM; ++h) {
        const float* wq = W + h * 2 * CDIM;      // uniform -> s_load
        float a = acc[h];
#pragma unroll
        for (int j = 0; j < 16; ++j) {
            a = fmaf(xq[j].x, wq[4 * j + 0], a);
            a = fmaf(xq[j].y, wq[4 * j + 1], a);
            a = fmaf(xq[j].z, wq[4 * j + 2], a);
            a = fmaf(xq[j].w, wq[4 * j + 3], a);
        }
        acc[h] = a;
    }
#pragma unroll
    for (int h = 0; h < HDIM; ++h) {
        const float* wk = W + h * 2 * CDIM + CDIM;
        float a = acc[h];
#pragma unroll
        for (int j = 0; j < 16; ++j) {
            a = fmaf(xk[j].x, wk[4 * j + 0], a);
            a = fmaf(xk[j].y, wk[4 * j + 1], a);
            a = fmaf(xk[j].z, wk[4 * j + 2], a);
            a = fmaf(xk[j].w, wk[4 * j + 3], a);
        }
        acc[h] = a;
    }

    float val[HDIM];
    float psum[HDIM];
#pragma unroll
    for (int h = 0; h < HDIM; ++h) {
        float v = __expf(acc[h] + bias[h]) * mval;
        val[h]  = v;
        psum[h] = v;
    }

    // block-wide sum over n (axis=2): wave butterfly, then cross-wave via LDS
#pragma unroll
    for (int h = 0; h < HDIM; ++h) {
        float s = psum[h];
#pragma unroll
        for (int off = 32; off >= 1; off >>= 1)
            s += __shfl_xor(s, off, 64);
        psum[h] = s;
    }
    const int lane = t & 63;
    const int wid  = t >> 6;
    if (lane == 0) {
#pragma unroll
        for (int h = 0; h < HDIM; ++h) red[wid * HDIM + h] = psum[h];
    }
    __syncthreads();
    if (t < HDIM) {
        float s = 0.0f;
#pragma unroll
        for (int w = 0; w < NWAVE; ++w) s += red[w * HDIM + t];
        rsum_lds[t] = 1.0f / s;
    }
    __syncthreads();

    float rs[HDIM];
#pragma unroll
    for (int h = 0; h < HDIM; ++h) rs[h] = rsum_lds[h];

    float* orow = out + (size_t)bm * NDIM * HDIM;
    float4 lo = make_float4(val[0] * rs[0], val[1] * rs[1],
                            val[2] * rs[2], val[3] * rs[3]);
    float4 hi = make_float4(val[4] * rs[4], val[5] * rs[5],
                            val[6] * rs[6], val[7] * rs[7]);
    float4* op = (float4*)(orow + (size_t)t * HDIM);
    op[0] = lo;
    op[1] = hi;
}

extern "C" void kernel_launch(void* const* d_in, const int* in_sizes, int n_in,
                              void* d_out, int out_size, void* d_ws, size_t ws_size,
                              hipStream_t stream) {
    const float* q    = (const float*)d_in[0];
    const float* k    = (const float*)d_in[1];
    const float* mask = (const float*)d_in[2];
    const float* W    = (const float*)d_in[3];
    const float* b    = (const float*)d_in[4];
    float* out = (float*)d_out;

    hipLaunchKernelGGL(mha_kernel, dim3(2 * NDIM), dim3(BDIM), 0, stream,
                       q, k, mask, W, b, out);
}